// Round 9
// baseline (161.117 us; speedup 1.0000x reference)
//
#include <hip/hip_runtime.h>
#include <cstdint>
#include <cstddef>

// ---------------- types / helpers ----------------
typedef __attribute__((ext_vector_type(8))) __bf16 bf16x8;
typedef __attribute__((ext_vector_type(4))) float  f32x4;

#define MFMA16(a, b, c) __builtin_amdgcn_mfma_f32_16x16x32_bf16((a), (b), (c), 0, 0, 0)

#define T_SEQ 4096
#define NHEADS 8
#define DH 64
#define NROWS (2 * NHEADS * T_SEQ)   // 65536 total (bh, q) rows
#define NEG_INF (-__builtin_huge_valf())
// 1/sqrt(64) * log2(e)  (softmax done in exp2 domain)
#define SCALE_Q 0.18033688011112042f

__device__ __forceinline__ unsigned short f2bf(float f) {
  unsigned int u = __float_as_uint(f);
  u += 0x7fffu + ((u >> 16) & 1u);
  return (unsigned short)(u >> 16);
}

// pack two f32 -> two bf16 in one u32 (round-half-up; a = low half)
__device__ __forceinline__ unsigned int pack_bf2(float a, float b) {
  unsigned int au = __float_as_uint(a) + 0x8000u;
  unsigned int bu = __float_as_uint(b) + 0x8000u;
  return (au >> 16) | (bu & 0xffff0000u);
}

// async global->LDS, 16B per lane. LDS dest = uniform base + lane*16.
__device__ __forceinline__ void gload16(const unsigned short* g, unsigned short* l) {
  __builtin_amdgcn_global_load_lds(
      (const __attribute__((address_space(1))) unsigned short*)g,
      (__attribute__((address_space(3))) unsigned short*)l, 16, 0, 0);
}

// ---------------- conversion kernels ----------------
__global__ void cvt_x_kernel(const float* __restrict__ x,
                             unsigned short* __restrict__ xb, int n4) {
  int i = blockIdx.x * blockDim.x + threadIdx.x;
  if (i >= n4) return;
  float4 v = ((const float4*)x)[i];
  ushort4 o;
  o.x = f2bf(v.x); o.y = f2bf(v.y); o.z = f2bf(v.z); o.w = f2bf(v.w);
  ((ushort4*)xb)[i] = o;
}

// w [512][N] (K=512 rows) -> wT [N][512] bf16
__global__ void cvt_T_kernel(const float* __restrict__ w,
                             unsigned short* __restrict__ wT, int N, int total) {
  int i = blockIdx.x * blockDim.x + threadIdx.x;
  if (i >= total) return;
  int n = i >> 9, k = i & 511;
  wT[i] = f2bf(w[(size_t)k * N + n]);
}

// ---------------- GEMM: C = A[M,K] * BT[N,K]^T + bias ----------------
// 128x128 block tile, BK=32, 4 waves (each a 64x64 quadrant), 16x16x32 MFMA.
// EPI==0: QKV epilogue (q/k -> [B*H][T][64], V -> transposed [B*H][64][T])
// EPI==1: fp32 output [M][512] with bias
template <int EPI>
__global__ __launch_bounds__(256) void gemm_bt(
    const unsigned short* __restrict__ A,
    const unsigned short* __restrict__ BT,
    const float* __restrict__ bias,
    float* __restrict__ outf,
    unsigned short* __restrict__ oq,
    unsigned short* __restrict__ ok,
    unsigned short* __restrict__ ovT,
    int K) {
  __shared__ alignas(16) unsigned short As[128 * 32];
  __shared__ alignas(16) unsigned short Bs[128 * 32];

  const int t = threadIdx.x;
  const int lane = t & 63;
  const int w = t >> 6;
  const int wr = (w >> 1) * 64;
  const int wc = (w & 1) * 64;
  const int g = lane >> 4, c = lane & 15;
  const int row0 = blockIdx.y * 128, col0 = blockIdx.x * 128;

  const int crow = t >> 2;          // 0..63
  const int ccol = (t & 3) * 8;     // 0,8,16,24
  const unsigned short* Ag0 = A + (size_t)(row0 + crow) * K + ccol;
  const unsigned short* Ag1 = A + (size_t)(row0 + 64 + crow) * K + ccol;
  const unsigned short* Bg0 = BT + (size_t)(col0 + crow) * K + ccol;
  const unsigned short* Bg1 = BT + (size_t)(col0 + 64 + crow) * K + ccol;

  f32x4 acc[4][4] = {};

  for (int k0 = 0; k0 < K; k0 += 32) {
    int4 a0 = *(const int4*)(Ag0 + k0);
    int4 a1 = *(const int4*)(Ag1 + k0);
    int4 b0 = *(const int4*)(Bg0 + k0);
    int4 b1 = *(const int4*)(Bg1 + k0);
    __syncthreads();
    *(int4*)&As[crow * 32 + ccol] = a0;
    *(int4*)&As[(64 + crow) * 32 + ccol] = a1;
    *(int4*)&Bs[crow * 32 + ccol] = b0;
    *(int4*)&Bs[(64 + crow) * 32 + ccol] = b1;
    __syncthreads();

    bf16x8 af[4], bfr[4];
#pragma unroll
    for (int m = 0; m < 4; ++m)
      af[m] = *(const bf16x8*)&As[(wr + m * 16 + c) * 32 + g * 8];
#pragma unroll
    for (int n = 0; n < 4; ++n)
      bfr[n] = *(const bf16x8*)&Bs[(wc + n * 16 + c) * 32 + g * 8];
#pragma unroll
    for (int m = 0; m < 4; ++m)
#pragma unroll
      for (int n = 0; n < 4; ++n)
        acc[m][n] = MFMA16(af[m], bfr[n], acc[m][n]);
  }

  // epilogue. D layout: row = g*4 + i, col = c (verified m89/m91 mapping)
#pragma unroll
  for (int m = 0; m < 4; ++m) {
#pragma unroll
    for (int n = 0; n < 4; ++n) {
      const int col = col0 + wc + n * 16 + c;
      const float bv = bias[col];
      if constexpr (EPI == 0) {
        const int which = col >> 9;          // wave-uniform (depends on block,n)
        const int h = (col >> 6) & 7;
        const int dh = col & 63;
        const int r0 = row0 + wr + m * 16 + g * 4;
        const int bb = r0 >> 12;             // r0 / T_SEQ (4 rows never cross)
        const int tt0 = r0 & 4095;
        if (which == 2) {
          // V transposed: vT[(bb*H + h)*64 + dh][tt0..tt0+3] -- contiguous
          ushort4 pk;
          pk.x = f2bf(acc[m][n][0] + bv);
          pk.y = f2bf(acc[m][n][1] + bv);
          pk.z = f2bf(acc[m][n][2] + bv);
          pk.w = f2bf(acc[m][n][3] + bv);
          *(ushort4*)&ovT[((size_t)((bb * NHEADS + h) * DH + dh)) * T_SEQ + tt0] = pk;
        } else {
          unsigned short* dst = (which == 0) ? oq : ok;
          const float sc = (which == 0) ? SCALE_Q : 1.0f;
#pragma unroll
          for (int i = 0; i < 4; ++i) {
            const size_t idx =
                ((size_t)((bb * NHEADS + h) * T_SEQ + tt0 + i)) * DH + dh;
            dst[idx] = f2bf((acc[m][n][i] + bv) * sc);
          }
        }
      } else {
#pragma unroll
        for (int i = 0; i < 4; ++i) {
          const int row = row0 + wr + m * 16 + g * 4 + i;
          outf[(size_t)row * 512 + col] = acc[m][n][i] + bv;
        }
      }
    }
  }
}

// ---------------- flash attention (causal, split-K) ----------------
// grid (B*H, 32, 2). Block (bh, y, hv) runs two flash passes (q-block y and
// 63-y), but only key-tile half hv of each: h0 = tiles [0, ceil((q+1)/2)),
// h1 = the rest. Every block does 32-33 tiles -> 1024 equal blocks = 4/CU
// (LDS 4 x 40KB = 160KB exactly) = 16 waves/CU, double round 8's occupancy.
// Each half emits normalized partial o (bf16) + s = m + log2(l); merge_kernel
// combines. Swapped QK^T / defer-max / XOR-swizzle as in round 8.
__global__ __launch_bounds__(256) void attn_kernel(
    const unsigned short* __restrict__ qb,
    const unsigned short* __restrict__ kb,
    const unsigned short* __restrict__ vtb,
    unsigned short* __restrict__ ob0,
    unsigned short* __restrict__ ob1,
    float* __restrict__ sb) {
  const int bh = blockIdx.x;
  const int y = blockIdx.y;
  const int hv = blockIdx.z;
  const int w = threadIdx.x >> 6;
  const int lane = threadIdx.x & 63;
  const int g = lane >> 4, c = lane & 15;

  // K tile: rows = key (64), cols = d (64, 128B). V tile: rows = d, cols = t.
  __shared__ alignas(16) unsigned short Ks[2][64 * 64];
  __shared__ alignas(16) unsigned short Vs[2][64 * 64];
  __shared__ alignas(16) unsigned short Plds[4][16 * 64];

  const unsigned short* Qp  = qb + (size_t)bh * T_SEQ * DH;
  const unsigned short* Kp  = kb + (size_t)bh * T_SEQ * DH;
  const unsigned short* VTp = vtb + (size_t)bh * DH * T_SEQ;

  unsigned short* obh = hv ? ob1 : ob0;
  float* sbh = sb + (size_t)hv * (2 * NHEADS * T_SEQ) + (size_t)bh * T_SEQ;

  // staging: wave w stages LDS rows 16w..16w+15 of both tiles (2 gloads each).
  // source column pre-swizzled: row r keeps byte-col cb at cb ^ ((r&7)<<4);
  // gload instr writes rows q*8+l8 linearly, so swizzle = 8*(lc ^ l8) elems.
  const int l8 = lane >> 3, lc = lane & 7;
  const int swzE = 8 * (lc ^ l8);
  const unsigned short* Ksrc0 = Kp + (size_t)(16 * w + l8) * DH + swzE;
  const unsigned short* Ksrc1 = Kp + (size_t)(16 * w + 8 + l8) * DH + swzE;
  const unsigned short* Vsrc0 = VTp + (size_t)(16 * w + l8) * T_SEQ + swzE;
  const unsigned short* Vsrc1 = VTp + (size_t)(16 * w + 8 + l8) * T_SEQ + swzE;

#define STAGE(B, J0) do {                                              \
    gload16(Ksrc0 + (size_t)(J0) * DH, &Ks[B][(2 * w) * 512]);         \
    gload16(Ksrc1 + (size_t)(J0) * DH, &Ks[B][(2 * w + 1) * 512]);     \
    gload16(Vsrc0 + (J0), &Vs[B][(2 * w) * 512]);                      \
    gload16(Vsrc1 + (J0), &Vs[B][(2 * w + 1) * 512]);                  \
  } while (0)

  const int swb = (c & 7) << 4;  // read-side xor (bytes)
  char* Pw = (char*)&Plds[w][0];

  for (int pass = 0; pass < 2; ++pass) {
    const int qblk = pass ? (63 - y) : y;
    const int qw0 = qblk * 64 + w * 16;
    const int split = (qblk + 2) >> 1;          // ceil((qblk+1)/2)
    const int t0 = hv ? split : 0;
    const int t1 = hv ? (qblk + 1) : split;

    // Q fragments (B-operand of swapped QK^T): row = c, k = g*8.. (+32)
    bf16x8 qf0 = *(const bf16x8*)&Qp[(size_t)(qw0 + c) * DH + g * 8];
    bf16x8 qf1 = *(const bf16x8*)&Qp[(size_t)(qw0 + c) * DH + 32 + g * 8];

    f32x4 acc[4] = {};
    float mi = NEG_INF;   // running row-max for q = qw0 + c (exp2 domain)
    float li = 0.f;       // running row-sum for q = qw0 + c

    if (t0 < t1) {  // block-uniform
      STAGE(0, t0 * 64);
      __syncthreads();  // compiler drains vmcnt(0) before s_barrier
      int cur = 0;

      for (int t = t0; t < t1; ++t) {
        if (t + 1 < t1) STAGE(cur ^ 1, (t + 1) * 64);

        const char* Kb = (const char*)&Ks[cur][0];
        const char* Vb = (const char*)&Vs[cur][0];

        // S tile (SWAPPED): s[ks][i] = S[key = t*64+ks*16+g*4+i][q = qw0+c]
        f32x4 s[4];
#pragma unroll
        for (int ks = 0; ks < 4; ++ks) {
          const int rb = (ks * 16 + c) * 128;
          bf16x8 kf0 = *(const bf16x8*)(Kb + rb + ((16 * g) ^ swb));
          bf16x8 kf1 = *(const bf16x8*)(Kb + rb + ((64 + 16 * g) ^ swb));
          f32x4 z = {0.f, 0.f, 0.f, 0.f};
          z = MFMA16(kf0, qf0, z);
          z = MFMA16(kf1, qf1, z);
          s[ks] = z;
        }

        // V fragments early -- independent of softmax, overlap ds latency
        bf16x8 vf0[4], vf1[4];
#pragma unroll
        for (int dt = 0; dt < 4; ++dt) {
          const int rb = (dt * 16 + c) * 128;
          vf0[dt] = *(const bf16x8*)(Vb + rb + ((16 * g) ^ swb));
          vf1[dt] = *(const bf16x8*)(Vb + rb + ((64 + 16 * g) ^ swb));
        }

        if (t == qblk) {  // diagonal tile: causal mask (key > q)
          const int qq = qw0 + c;
#pragma unroll
          for (int ks = 0; ks < 4; ++ks)
#pragma unroll
            for (int i = 0; i < 4; ++i) {
              const int key = t * 64 + ks * 16 + g * 4 + i;
              if (key > qq) s[ks][i] = NEG_INF;
            }
        }

        // row max: 15 local fmax + 2 cross-g shuffles (replicated over g)
        float m0 = fmaxf(fmaxf(s[0][0], s[0][1]), fmaxf(s[0][2], s[0][3]));
        float m1 = fmaxf(fmaxf(s[1][0], s[1][1]), fmaxf(s[1][2], s[1][3]));
        float m2 = fmaxf(fmaxf(s[2][0], s[2][1]), fmaxf(s[2][2], s[2][3]));
        float m3 = fmaxf(fmaxf(s[3][0], s[3][1]), fmaxf(s[3][2], s[3][3]));
        float mloc = fmaxf(fmaxf(m0, m1), fmaxf(m2, m3));
        mloc = fmaxf(mloc, __shfl_xor(mloc, 16));
        mloc = fmaxf(mloc, __shfl_xor(mloc, 32));

        // defer-max: only rescale when some row grew past THR=8
        if (__ballot(mloc > mi + 8.0f) != 0ull) {
          const float mn = fmaxf(mi, mloc);
          const float scq = exp2f(mi - mn);
          mi = mn;
          li *= scq;
          // redistribute sc to the acc layout (q = g*4+i lives at lane 4g+i)
          const float sv0 = __shfl(scq, 4 * g + 0);
          const float sv1 = __shfl(scq, 4 * g + 1);
          const float sv2 = __shfl(scq, 4 * g + 2);
          const float sv3 = __shfl(scq, 4 * g + 3);
#pragma unroll
          for (int dt = 0; dt < 4; ++dt) {
            acc[dt][0] *= sv0; acc[dt][1] *= sv1;
            acc[dt][2] *= sv2; acc[dt][3] *= sv3;
          }
        }

        // p = exp2(s - mi), local sum, packed bf16 stores (4 x 8B per lane)
        float ls = 0.f;
#pragma unroll
        for (int ks = 0; ks < 4; ++ks) {
          float p0 = exp2f(s[ks][0] - mi);
          float p1 = exp2f(s[ks][1] - mi);
          float p2 = exp2f(s[ks][2] - mi);
          float p3 = exp2f(s[ks][3] - mi);
          ls += (p0 + p1) + (p2 + p3);
          uint2 pk;
          pk.x = pack_bf2(p0, p1);
          pk.y = pack_bf2(p2, p3);
          // keys 16ks+4g..+3 of row q=c, swizzled with the same involution
          *(uint2*)(Pw + c * 128 + ((32 * ks + 8 * g) ^ swb)) = pk;
        }
        ls += __shfl_xor(ls, 16);
        ls += __shfl_xor(ls, 32);
        li += ls;

        // wave-private LDS RAW: P stores must land before the A-frag read
        asm volatile("s_waitcnt lgkmcnt(0)" ::: "memory");

        bf16x8 pf0 = *(const bf16x8*)(Pw + c * 128 + ((16 * g) ^ swb));
        bf16x8 pf1 = *(const bf16x8*)(Pw + c * 128 + ((64 + 16 * g) ^ swb));

#pragma unroll
        for (int dt = 0; dt < 4; ++dt) {
          acc[dt] = MFMA16(pf0, vf0[dt], acc[dt]);
          acc[dt] = MFMA16(pf1, vf1[dt], acc[dt]);
        }

        // barrier: publishes prefetched tile (vmcnt drain) + buf-reuse guard
        __syncthreads();
        cur ^= 1;
      }
    }

    // partial epilogue: o_norm (bf16) + s = mi + log2(li) per q-row.
    // li/mi for row qw0+c live at lane c (any g); acc rows are g*4+i.
    if (g == 0) {
      sbh[qw0 + c] = (li > 0.f) ? (mi + log2f(li)) : NEG_INF;
    }
    const float liq0 = __shfl(li, 4 * g + 0);
    const float liq1 = __shfl(li, 4 * g + 1);
    const float liq2 = __shfl(li, 4 * g + 2);
    const float liq3 = __shfl(li, 4 * g + 3);
    const float inv[4] = {liq0 > 0.f ? 1.0f / liq0 : 0.f,
                          liq1 > 0.f ? 1.0f / liq1 : 0.f,
                          liq2 > 0.f ? 1.0f / liq2 : 0.f,
                          liq3 > 0.f ? 1.0f / liq3 : 0.f};
#pragma unroll
    for (int i = 0; i < 4; ++i) {
      const int qq = qw0 + g * 4 + i;
      const size_t base = ((size_t)bh * T_SEQ + qq) * DH;
#pragma unroll
      for (int dt = 0; dt < 4; ++dt)
        obh[base + dt * 16 + c] = f2bf(acc[dt][i] * inv[i]);
    }
  }
#undef STAGE
}

// ---------------- split-K merge ----------------
// y[(b*T+q)*512 + h*64 + d] = (w0*o0 + w1*o1), w_i = 2^(s_i - max) normalized.
// 256 threads = 32 rows x 8 dim-segments (8 bf16 = 16B each).
__global__ __launch_bounds__(256) void merge_kernel(
    const unsigned short* __restrict__ ob0,
    const unsigned short* __restrict__ ob1,
    const float* __restrict__ sb,
    unsigned short* __restrict__ yb) {
  const int t = threadIdx.x;
  const int r = blockIdx.x * 32 + (t >> 3);   // global (bh,q) row, 0..65535
  const int dseg = (t & 7) * 8;
  const float s0 = sb[r];
  const float s1 = sb[NROWS + r];
  const float S = fmaxf(s0, s1);
  const float w0 = exp2f(s0 - S);
  const float w1 = exp2f(s1 - S);
  const float inv = 1.0f / (w0 + w1);
  const float a0 = w0 * inv, a1 = w1 * inv;
  const uint4 u0 = *(const uint4*)&ob0[(size_t)r * DH + dseg];
  const uint4 u1 = *(const uint4*)&ob1[(size_t)r * DH + dseg];
  const unsigned int* p0 = (const unsigned int*)&u0;
  const unsigned int* p1 = (const unsigned int*)&u1;
  unsigned int ow[4];
#pragma unroll
  for (int j = 0; j < 4; ++j) {
    const float lo0 = __uint_as_float(p0[j] << 16);
    const float hi0 = __uint_as_float(p0[j] & 0xffff0000u);
    const float lo1 = __uint_as_float(p1[j] << 16);
    const float hi1 = __uint_as_float(p1[j] & 0xffff0000u);
    ow[j] = pack_bf2(a0 * lo0 + a1 * lo1, a0 * hi0 + a1 * hi1);
  }
  const int bh = r >> 12, q = r & 4095;
  const int bb = bh >> 3, hh = bh & 7;
  *(uint4*)&yb[((size_t)(bb * T_SEQ + q)) * 512 + hh * DH + dseg] = *(uint4*)ow;
}

// ---------------- launch ----------------
extern "C" void kernel_launch(void* const* d_in, const int* in_sizes, int n_in,
                              void* d_out, int out_size, void* d_ws, size_t ws_size,
                              hipStream_t stream) {
  const float* x     = (const float*)d_in[0];
  const float* w_qkv = (const float*)d_in[1];
  const float* b_qkv = (const float*)d_in[2];
  const float* w_out = (const float*)d_in[3];
  const float* b_out = (const float*)d_in[4];
  float* out = (float*)d_out;

  char* p = (char*)d_ws;
  unsigned short* xb    = (unsigned short*)p; p += (size_t)8192 * 512 * 2;
  unsigned short* wqkvT = (unsigned short*)p; p += (size_t)1536 * 512 * 2;
  unsigned short* woutT = (unsigned short*)p; p += (size_t)512 * 512 * 2;
  unsigned short* qbuf  = (unsigned short*)p; p += (size_t)16 * T_SEQ * DH * 2;
  unsigned short* kbuf  = (unsigned short*)p; p += (size_t)16 * T_SEQ * DH * 2;
  unsigned short* vtbuf = (unsigned short*)p; p += (size_t)16 * T_SEQ * DH * 2;
  unsigned short* ybuf  = (unsigned short*)p; p += (size_t)8192 * 512 * 2;
  unsigned short* ob1   = (unsigned short*)p; p += (size_t)16 * T_SEQ * DH * 2;
  float*          sbuf  = (float*)p;          p += (size_t)2 * NROWS * 4;
  unsigned short* ob0   = xb;  // xb is dead after the QKV GEMM -- reuse

  cvt_x_kernel<<<4096, 256, 0, stream>>>(x, xb, 8192 * 512 / 4);
  cvt_T_kernel<<<3072, 256, 0, stream>>>(w_qkv, wqkvT, 1536, 1536 * 512);
  cvt_T_kernel<<<1024, 256, 0, stream>>>(w_out, woutT, 512, 512 * 512);

  // QKV projection: M=8192, N=1536, K=512
  gemm_bt<0><<<dim3(12, 64), 256, 0, stream>>>(xb, wqkvT, b_qkv, nullptr,
                                               qbuf, kbuf, vtbuf, 512);
  // attention: split-K halves (1024 equal blocks = 4/CU), then merge
  attn_kernel<<<dim3(16, 32, 2), 256, 0, stream>>>(qbuf, kbuf, vtbuf,
                                                   ob0, ob1, sbuf);
  merge_kernel<<<NROWS / 32, 256, 0, stream>>>(ob0, ob1, sbuf, ybuf);
  // output projection: M=8192, N=512, K=512
  gemm_bt<1><<<dim3(4, 64), 256, 0, stream>>>(ybuf, woutT, b_out, out,
                                              nullptr, nullptr, nullptr, 512);
}